// Round 12
// baseline (116.169 us; speedup 1.0000x reference)
//
#include <hip/hip_runtime.h>
#include <hip/hip_bf16.h>

#define NFFT   4194304
#define NMODES 2
#define NTAPS  101
#define NVALID (NFFT - NTAPS + 1)   // 4194204
#define N0     (NTAPS / 2)          // 50

constexpr int BLOCK = 64;                           // ONE wave per block
constexpr int TILE  = 512;                          // output samples per wave
constexpr int NT    = (NVALID + TILE - 1) / TILE;   // 8192 blocks
constexpr int WIN   = 640;                          // staged P samples (max read idx 615)
constexpr int NCH   = WIN / 2;                      // 320 16B chunks per x array
constexpr int NM    = 15;                           // banded MFMA accumulation steps
constexpr int TBW   = 272;                          // compact B-table words

// Wave-private LDS: xaR[0..1279] | xbR[1280..2559] | Pl[2560..3199] | Bt[3200..3471]
constexpr int OXB = 1280;
constexpr int OPL = 2560;
constexpr int OBT = 3200;
constexpr int LWORDS = 3472;                        // 13888 B -> 11 blocks/CU

typedef __attribute__((ext_vector_type(8)))  short short8;
typedef __attribute__((ext_vector_type(16))) float float16;

static __device__ __forceinline__ unsigned short f2bf(float x) {
    __hip_bfloat16 h = __float2bfloat16(x);
    return *reinterpret_cast<unsigned short*>(&h);
}
static __device__ __forceinline__ unsigned pk(float e0, float e1) {
    return (unsigned)f2bf(e0) | ((unsigned)f2bf(e1) << 16);
}
// XOR word bits 2..4 with word bits 5..7: bijective, preserves aligned 4-word groups,
// spreads 64B-stride accesses across banks (residual 2-way = free).
static __device__ __forceinline__ int swz(int s) {
    return s ^ (((s >> 5) & 7) << 2);
}
// HBM -> LDS direct (16B/lane, no VGPR round trip). Dest must be linear:
// this lane's pointer == wave-uniform base + lane*16 (holds for c = uniform + lane).
static __device__ __forceinline__ void gl16(const float4* g, unsigned* l) {
    __builtin_amdgcn_global_load_lds(
        (const __attribute__((address_space(1))) void*)g,
        (__attribute__((address_space(3))) void*)l, 16, 0, 0);
}

__global__ __launch_bounds__(BLOCK, 4) void nl_kernel(
    const float* __restrict__ xa,   // d_in[0] big stream (A = xr)
    const float* __restrict__ xb,   // d_in[1] big stream (B = xi)
    const float* __restrict__ W,  const float* __restrict__ b,
    const float* __restrict__ power, unsigned* __restrict__ out)
{
    // Entirely wave-private -> NO __syncthreads anywhere in this kernel.
    __shared__ __align__(16) unsigned lds[LWORDS];
    unsigned* const xaR = lds;
    unsigned* const xbR = lds + OXB;
    unsigned* const Pl  = lds + OPL;
    unsigned* const Bt  = lds + OBT;

    const int lane = threadIdx.x & 63;
    const int colc = lane & 31;      // B/C column = (c_s<<1)|o ; also A row index
    const int h    = lane >> 5;      // k half: k = 8h + e
    const int cs   = colc >> 1;      // fine shift 0..15
    const int o    = colc & 1;       // output mode
    const int r    = colc;           // A row

    const int wstart = blockIdx.x * TILE;            // this wave's first output sample
    const int ts2    = wstart >> 1;                  // first 2-sample chunk

    // ---- 1) async stage raw xa/xb -> private LDS (10 x gl16 per lane) ----
    const float4* __restrict__ xa4 = reinterpret_cast<const float4*>(xa); // 2 samples
    const float4* __restrict__ xb4 = reinterpret_cast<const float4*>(xb);
    #pragma unroll
    for (int k = 0; k < 5; ++k) {
        const int c  = lane + 64 * k;                // chunk = uniform + lane (linear dest)
        const int cc = min(ts2 + c, NFFT / 2 - 1);   // clamp OOB (zeroed in P-compute)
        gl16(xa4 + cc, &xaR[4 * c]);
        gl16(xb4 + cc, &xbR[4 * c]);
    }

    // ---- compact B table while the DMA flies: Bt[(t+15)*2+o] = pk(W[t,0,o],W[t,1,o]) ----
    {
        const float4* __restrict__ Wt = reinterpret_cast<const float4*>(W);
        #pragma unroll
        for (int k = 0; k < 5; ++k) {
            const int idx = lane + 64 * k;
            if (k < 4 || idx < TBW) {
                const int t  = (idx >> 1) - 15;
                const int oo = idx & 1;
                const bool ok = (unsigned)t <= 100u;
                const float4 w = Wt[ok ? t : 0];
                Bt[idx] = ok ? pk(oo ? w.y : w.x, oo ? w.w : w.z) : 0u;
            }
        }
    }

    // Wave-private sync: drain the global->LDS DMA; fence keeps ds_reads behind it.
    asm volatile("s_waitcnt vmcnt(0)" ::: "memory");
    __builtin_amdgcn_sched_barrier(0);

    // ---- 2) P = xa^2 + xb^2 -> bf16x2 swizzled Pl (own chunks only) ----
    #pragma unroll
    for (int k = 0; k < 5; ++k) {
        const int tp = lane + 64 * k;                // chunk index 0..319
        const float4 a = *reinterpret_cast<const float4*>(&xaR[4 * tp]);
        const float4 c = *reinterpret_cast<const float4*>(&xbR[4 * tp]);
        const int g = wstart + 2 * tp;               // even; g,g+1 valid together
        unsigned u0 = 0u, u1 = 0u;
        if (g < NFFT) {
            u0 = pk(a.x * a.x + c.x * c.x, a.y * a.y + c.y * c.y);
            u1 = pk(a.z * a.z + c.z * c.z, a.w * a.w + c.w * c.w);
        }
        *reinterpret_cast<uint2*>(&Pl[swz(2 * tp)]) = make_uint2(u0, u1);
    }
    // intra-wave LDS RAW: compiler-inserted lgkmcnt ordering suffices.

    // ---- 3) 512-sample chunk: 15 x (b128 A + 4x b32 B + 32x32x16 MFMA) ----
    const int bbase = ((4 * h - cs + 15) << 1) | o;
    float16 acc = {};
    uint4 areg[4];                    // 4-deep A prefetch pipe (static idx post-unroll)
    #pragma unroll
    for (int m = 0; m < 4; ++m)
        areg[m] = *reinterpret_cast<const uint4*>(&Pl[swz(16 * r + 8 * m + 4 * h)]);
    #pragma unroll
    for (int m = 0; m < NM; ++m) {
        uint4 bq;
        bq.x = Bt[bbase + 16 * m + 0];
        bq.y = Bt[bbase + 16 * m + 2];
        bq.z = Bt[bbase + 16 * m + 4];
        bq.w = Bt[bbase + 16 * m + 6];
        acc = __builtin_amdgcn_mfma_f32_32x32x16_bf16(
                  __builtin_bit_cast(short8, areg[m & 3]),
                  __builtin_bit_cast(short8, bq), acc, 0, 0, 0);
        if (m + 4 < NM)
            areg[m & 3] = *reinterpret_cast<const uint4*>(
                              &Pl[swz(16 * r + 8 * (m + 4) + 4 * h)]);
    }

    // ---- 4) epilogue: direct from accumulators; x re-read from private raw copy ----
    // C/D: col = lane&31, row = (reg&3) + 8*(reg>>2) + 4*(lane>>5).
    // local x word = 2*(16*row + cs + N0) + o, max 1223 < 1280: always staged.
    const float bo   = o ? b[1] : b[0];
    const float coef = 0.066268f * exp10f(power[0] * 0.1f);
    const float* __restrict__ xaF = reinterpret_cast<const float*>(xaR);
    const float* __restrict__ xbF = reinterpret_cast<const float*>(xbR);

    if (blockIdx.x != NT - 1) {                       // full tile: branch-free
        #pragma unroll
        for (int j = 0; j < 16; ++j) {
            const int row = (j & 3) + 8 * (j >> 2) + 4 * h;
            const int lw  = 2 * (16 * row + cs + N0) + o;
            const float Ax = xaF[lw];
            const float Bx = xbF[lw];
            float sn, cn;
            __sincosf((acc[j] + bo) * coef, &sn, &cn);
            const int n = wstart + 16 * row + cs;
            __builtin_nontemporal_store(pk(Bx * cn - Ax * sn, Ax * cn + Bx * sn),
                                        &out[n * 2 + o]);
        }
    } else {                                          // tail tile: guarded stores
        #pragma unroll
        for (int j = 0; j < 16; ++j) {
            const int row = (j & 3) + 8 * (j >> 2) + 4 * h;
            const int n   = wstart + 16 * row + cs;
            if (n < NVALID) {
                const int lw  = 2 * (16 * row + cs + N0) + o;
                const float Ax = xaF[lw];
                const float Bx = xbF[lw];
                float sn, cn;
                __sincosf((acc[j] + bo) * coef, &sn, &cn);
                __builtin_nontemporal_store(pk(Bx * cn - Ax * sn, Ax * cn + Bx * sn),
                                            &out[n * 2 + o]);
            }
        }
    }
}

extern "C" void kernel_launch(void* const* d_in, const int* in_sizes, int n_in,
                              void* d_out, int out_size, void* d_ws, size_t ws_size,
                              hipStream_t stream) {
    // Bind by size (robust): big arrays = x streams, 404 = W, 2 = b, 1 = power.
    const float* big[2] = {nullptr, nullptr};
    const float* W = nullptr; const float* b = nullptr; const float* power = nullptr;
    int nbig = 0;
    for (int i = 0; i < n_in; ++i) {
        const float* p = (const float*)d_in[i];
        const int sz = in_sizes[i];
        if (sz == NFFT * NMODES)       { if (nbig < 2) big[nbig++] = p; }
        else if (sz == NTAPS * NMODES * NMODES) { W = p; }
        else if (sz == NMODES)         { b = p; }
        else if (sz == 1)              { power = p; }
    }

    unsigned* out = (unsigned*)d_out;
    nl_kernel<<<NT, BLOCK, 0, stream>>>(big[0], big[1], W, b, power, out);
}